// Round 1
// baseline (196.254 us; speedup 1.0000x reference)
//
#include <hip/hip_runtime.h>
#include <math.h>

// Problem constants (from reference)
#define NN 8192
#define FF 128
#define ORD 2
#define CSR_STRIDE 128   // per-row column-index capacity; mean nnz ~33, P(>128) ~ 0

// ---------------------------------------------------------------------------
// Kernel 1: xw = x @ W   [N,128] x [128,128] -> [N,128]
// One block per row, 128 threads (thread f owns output feature f).
// ---------------------------------------------------------------------------
__global__ __launch_bounds__(128) void xw_kernel(const float* __restrict__ x,
                                                 const float* __restrict__ W,
                                                 float* __restrict__ xw) {
    const int i = blockIdx.x;
    const int f = threadIdx.x;
    __shared__ float xs[FF];
    xs[f] = x[(size_t)i * FF + f];
    __syncthreads();
    float acc = 0.f;
#pragma unroll 8
    for (int k = 0; k < FF; ++k) {
        acc += xs[k] * W[k * FF + f];   // W row read is coalesced across threads
    }
    xw[(size_t)i * FF + f] = acc;
}

// ---------------------------------------------------------------------------
// Kernel 2: single streaming scan of adj_powers.
// One block per (order, row). Computes degree -> dinv, and (if it fits)
// writes the row's nonzero column indices into a fixed-stride CSR slab.
// Deterministic compaction order: (thread t, then iteration s, then lane e).
// Coalesced: iteration s reads float4 at [s*256 + t] -> 1 KiB/wave-instr.
// ---------------------------------------------------------------------------
__global__ __launch_bounds__(256) void scan_kernel(const float* __restrict__ adj,
                                                   float* __restrict__ dinv,
                                                   int* __restrict__ cnt,
                                                   int* __restrict__ colidx,
                                                   int csr_ok) {
    const int bid = blockIdx.x;          // o*NN + i
    const int i   = bid & (NN - 1);
    const int t   = threadIdx.x;

    const float4* row = (const float4*)(adj + (size_t)bid * NN);

    float4 v[8];
    int c = 0;
#pragma unroll
    for (int s = 0; s < 8; ++s) {
        const int p = s * 256 + t;       // float4 index; columns 4p..4p+3
        v[s] = row[p];
        const int j0 = 4 * p;
        if (v[s].x != 0.f && (j0 + 0) != i) ++c;
        if (v[s].y != 0.f && (j0 + 1) != i) ++c;
        if (v[s].z != 0.f && (j0 + 2) != i) ++c;
        if (v[s].w != 0.f && (j0 + 3) != i) ++c;
    }

    // Block-wide inclusive prefix sum (Hillis-Steele) over 256 counts.
    __shared__ int ps[256];
    ps[t] = c;
    __syncthreads();
    for (int off = 1; off < 256; off <<= 1) {
        const int val = (t >= off) ? ps[t - off] : 0;
        __syncthreads();
        ps[t] += val;
        __syncthreads();
    }
    const int total = ps[255];
    const int myoff = ps[t] - c;         // exclusive prefix

    if (t == 0) {
        cnt[bid]  = total;
        dinv[bid] = 1.0f / sqrtf((float)(total + 1));   // deg = total + 1 (forced diag)
    }

    if (csr_ok && total <= CSR_STRIDE) {
        int* outp = colidx + (size_t)bid * CSR_STRIDE + myoff;
#pragma unroll
        for (int s = 0; s < 8; ++s) {
            const int p  = s * 256 + t;
            const int j0 = 4 * p;
            if (v[s].x != 0.f && (j0 + 0) != i) *outp++ = j0 + 0;
            if (v[s].y != 0.f && (j0 + 1) != i) *outp++ = j0 + 1;
            if (v[s].z != 0.f && (j0 + 2) != i) *outp++ = j0 + 2;
            if (v[s].w != 0.f && (j0 + 3) != i) *outp++ = j0 + 3;
        }
    }
}

// ---------------------------------------------------------------------------
// Kernel 3: gather + combine orders.
// One block per output row i, 256 threads = 2 halves x 128 features.
// Half h accumulates queue entries e = h, h+2, ... ; halves combined at end
// (fixed order -> deterministic FP sum).
// ---------------------------------------------------------------------------
__global__ __launch_bounds__(256) void gather_kernel(const float* __restrict__ adj,
                                                     const float* __restrict__ xw,
                                                     const float* __restrict__ dinv,
                                                     const int* __restrict__ cnt,
                                                     const int* __restrict__ colidx,
                                                     const float* __restrict__ bias,
                                                     const float* __restrict__ alpha,
                                                     float* __restrict__ out,
                                                     int csr_ok) {
    const int i = blockIdx.x;
    const int t = threadIdx.x;
    const int f = t & (FF - 1);
    const int h = t >> 7;                 // 0 or 1

    __shared__ float hsum[FF];
    float result = 0.f;

    for (int o = 0; o < ORD; ++o) {
        const int bid = o * NN + i;
        const int c   = cnt[bid];
        float acc = 0.f;
        if (h == 0) acc = dinv[bid] * xw[(size_t)i * FF + f];   // forced diagonal term

        if (csr_ok && c <= CSR_STRIDE) {
            const int* q = colidx + (size_t)bid * CSR_STRIDE;
            for (int e = h; e < c; e += 2) {
                const int j = q[e];                       // broadcast read
                acc += dinv[o * NN + j] * xw[(size_t)j * FF + f];  // coalesced 512B
            }
        } else {
            // Dense fallback (never expected to trigger): half h scans its half row.
            const float* row = adj + (size_t)bid * NN;
            for (int j = h * (NN / 2); j < (h + 1) * (NN / 2); ++j) {
                const float a = row[j];
                if (a != 0.f && j != i) acc += dinv[o * NN + j] * xw[(size_t)j * FF + f];
            }
        }

        if (h == 1) hsum[f] = acc;
        __syncthreads();
        if (h == 0) {
            const float tot = acc + hsum[f];
            result += alpha[o] * (dinv[bid] * tot + bias[f]);
        }
        __syncthreads();   // protect hsum before next order
    }

    if (h == 0) out[(size_t)i * FF + f] = result;
}

// ---------------------------------------------------------------------------
extern "C" void kernel_launch(void* const* d_in, const int* in_sizes, int n_in,
                              void* d_out, int out_size, void* d_ws, size_t ws_size,
                              hipStream_t stream) {
    const float* x     = (const float*)d_in[0];
    // d_in[1] = edge_index (int64) -- unused by the math
    const float* adj   = (const float*)d_in[2];
    const float* W     = (const float*)d_in[3];
    const float* bias  = (const float*)d_in[4];
    const float* alpha = (const float*)d_in[5];
    float* out         = (float*)d_out;

    // Workspace layout
    char* ws = (char*)d_ws;
    size_t off = 0;
    float* xw   = (float*)(ws + off); off += (size_t)NN * FF * sizeof(float);   // 4 MiB
    float* dinv = (float*)(ws + off); off += (size_t)ORD * NN * sizeof(float);  // 64 KiB
    int*   cnt  = (int*)(ws + off);   off += (size_t)ORD * NN * sizeof(int);    // 64 KiB
    int*   colidx = (int*)(ws + off); off += (size_t)ORD * NN * CSR_STRIDE * sizeof(int); // 8 MiB
    const int csr_ok = (ws_size >= off) ? 1 : 0;

    hipLaunchKernelGGL(xw_kernel, dim3(NN), dim3(FF), 0, stream, x, W, xw);
    hipLaunchKernelGGL(scan_kernel, dim3(ORD * NN), dim3(256), 0, stream,
                       adj, dinv, cnt, colidx, csr_ok);
    hipLaunchKernelGGL(gather_kernel, dim3(NN), dim3(256), 0, stream,
                       adj, xw, dinv, cnt, colidx, bias, alpha, out, csr_ok);
}

// Round 2
// 154.309 us; speedup vs baseline: 1.2718x; 1.2718x over previous
//
#include <hip/hip_runtime.h>
#include <math.h>

// Problem constants (from reference)
#define NN 8192
#define FF 128
#define ORD 2
#define CSR_STRIDE 128     // per-row column-index capacity; mean nnz ~33, P(>128) ~ 0
#define XW_ROWS 16         // rows per xw-role block
#define XW_BLOCKS (NN / XW_ROWS)      // 512
#define SCAN_BLOCKS (ORD * NN)        // 16384

// ---------------------------------------------------------------------------
// Fused kernel 1: blocks [0, XW_BLOCKS) compute xw = x@W (L2/VALU-bound);
// blocks [XW_BLOCKS, XW_BLOCKS+SCAN_BLOCKS) stream-scan adj_powers (HBM-bound).
// The two roles overlap on the device, hiding the xw cost entirely.
// ---------------------------------------------------------------------------
__global__ __launch_bounds__(256) void scan_xw_kernel(
    const float* __restrict__ adj, const float* __restrict__ x,
    const float* __restrict__ W,
    float* __restrict__ xw, float* __restrict__ dinv,
    int* __restrict__ cnt, int* __restrict__ colidx, int csr_ok)
{
    const int t = threadIdx.x;

    if (blockIdx.x < XW_BLOCKS) {
        // ---------------- xw role: 16 rows x 128 cols per block -------------
        const int row0 = blockIdx.x * XW_ROWS;
        __shared__ float xsT[FF * 20];   // x tile transposed, [k][r], stride 20 (16B-aligned rows)
        for (int idx = t; idx < XW_ROWS * FF; idx += 256) {
            const int r = idx >> 7, k = idx & 127;
            xsT[k * 20 + r] = x[(size_t)(row0 + r) * FF + k];
        }
        __syncthreads();
        const int f = t & 127;
        const int h = t >> 7;            // rows h*8 .. h*8+7
        float acc[8];
#pragma unroll
        for (int r = 0; r < 8; ++r) acc[r] = 0.f;
#pragma unroll 4
        for (int k = 0; k < FF; ++k) {
            const float wk = W[k * FF + f];          // 64KB/block from L1/L2
            const float4* xp = (const float4*)&xsT[k * 20 + h * 8];
            const float4 a0 = xp[0], a1 = xp[1];     // broadcast LDS reads
            acc[0] += a0.x * wk; acc[1] += a0.y * wk;
            acc[2] += a0.z * wk; acc[3] += a0.w * wk;
            acc[4] += a1.x * wk; acc[5] += a1.y * wk;
            acc[6] += a1.z * wk; acc[7] += a1.w * wk;
        }
#pragma unroll
        for (int r = 0; r < 8; ++r)
            xw[(size_t)(row0 + h * 8 + r) * FF + f] = acc[r];
        return;
    }

    // ---------------- scan role: one (order,row) per block ------------------
    const int bid = blockIdx.x - XW_BLOCKS;   // o*NN + i
    const int i   = bid & (NN - 1);

    const float4* row = (const float4*)(adj + (size_t)bid * NN);

    float4 v[8];
    int c = 0;
#pragma unroll
    for (int s = 0; s < 8; ++s) {
        const int p = s * 256 + t;            // float4 index; columns 4p..4p+3
        v[s] = row[p];
        const int j0 = 4 * p;
        if (v[s].x != 0.f && (j0 + 0) != i) ++c;
        if (v[s].y != 0.f && (j0 + 1) != i) ++c;
        if (v[s].z != 0.f && (j0 + 2) != i) ++c;
        if (v[s].w != 0.f && (j0 + 3) != i) ++c;
    }

    // Wave-level inclusive scan (wave64), then cross-wave combine: 1 barrier.
    const int lane = t & 63;
    int incl = c;
#pragma unroll
    for (int d = 1; d < 64; d <<= 1) {
        const int n = __shfl_up(incl, d);
        if (lane >= d) incl += n;
    }
    __shared__ int wtot[4];
    if (lane == 63) wtot[t >> 6] = incl;
    __syncthreads();
    const int w = t >> 6;
    int woff = 0;
#pragma unroll
    for (int ww = 0; ww < 3; ++ww)
        if (ww < w) woff += wtot[ww];
    const int total = wtot[0] + wtot[1] + wtot[2] + wtot[3];
    const int myoff = woff + incl - c;        // exclusive prefix, deterministic order

    if (t == 0) {
        cnt[bid]  = total;
        dinv[bid] = 1.0f / sqrtf((float)(total + 1));   // deg = total + 1 (forced diag)
    }

    if (csr_ok && total <= CSR_STRIDE) {
        int* outp = colidx + (size_t)bid * CSR_STRIDE + myoff;
#pragma unroll
        for (int s = 0; s < 8; ++s) {
            const int p  = s * 256 + t;
            const int j0 = 4 * p;
            if (v[s].x != 0.f && (j0 + 0) != i) *outp++ = j0 + 0;
            if (v[s].y != 0.f && (j0 + 1) != i) *outp++ = j0 + 1;
            if (v[s].z != 0.f && (j0 + 2) != i) *outp++ = j0 + 2;
            if (v[s].w != 0.f && (j0 + 3) != i) *outp++ = j0 + 3;
        }
    }
}

// ---------------------------------------------------------------------------
// Kernel 2: gather + combine orders.
// One block per output row i, 512 threads = 4 quarters x 128 features.
// Indices + dinv weights staged in LDS once (coalesced); quarter q handles
// entries e = q, q+4, ... ; fixed-order combine -> deterministic FP sum.
// ---------------------------------------------------------------------------
__global__ __launch_bounds__(512) void gather_kernel(
    const float* __restrict__ adj, const float* __restrict__ xw,
    const float* __restrict__ dinv, const int* __restrict__ cnt,
    const int* __restrict__ colidx, const float* __restrict__ bias,
    const float* __restrict__ alpha, float* __restrict__ out, int csr_ok)
{
    const int i = blockIdx.x;
    const int t = threadIdx.x;
    const int f = t & 127;
    const int q = t >> 7;                 // 0..3

    __shared__ int   qj[ORD][CSR_STRIDE];
    __shared__ float qw[ORD][CSR_STRIDE];
    __shared__ float part[3][FF];
    __shared__ int   cs[ORD];

    if (t < ORD) cs[t] = cnt[t * NN + i];
    __syncthreads();
    const int c0 = cs[0], c1 = cs[1];

    // Stage column indices and their dinv weights (threads 0..255).
    if (t < 2 * CSR_STRIDE) {
        const int o  = t >> 7;
        const int e  = t & 127;
        const int cc = (o == 0) ? c0 : c1;
        if (csr_ok && cc <= CSR_STRIDE && e < cc) {
            const int j = colidx[(size_t)(o * NN + i) * CSR_STRIDE + e];
            qj[o][e] = j;
            qw[o][e] = dinv[o * NN + j];
        }
    }
    __syncthreads();

    float facc = 0.f;
    for (int o = 0; o < ORD; ++o) {
        const int   bidq = o * NN + i;
        const int   c    = (o == 0) ? c0 : c1;
        const float di   = dinv[bidq];
        float s = 0.f;
        if (q == 0) s = di * xw[(size_t)i * FF + f];       // forced diagonal term

        if (csr_ok && c <= CSR_STRIDE) {
            for (int e = q; e < c; e += 4)
                s += qw[o][e] * xw[(size_t)qj[o][e] * FF + f];
        } else {
            // Dense fallback (never expected): quarter q scans its row segment.
            const float* rowp = adj + (size_t)bidq * NN;
            for (int j = q * (NN / 4); j < (q + 1) * (NN / 4); ++j) {
                const float a = rowp[j];
                if (a != 0.f && j != i) s += dinv[o * NN + j] * xw[(size_t)j * FF + f];
            }
        }
        facc += alpha[o] * (di * s);
    }

    if (q > 0) part[q - 1][f] = facc;
    __syncthreads();
    if (q == 0) {
        const float res = facc + part[0][f] + part[1][f] + part[2][f]
                        + (alpha[0] + alpha[1]) * bias[f];
        out[(size_t)i * FF + f] = res;
    }
}

// ---------------------------------------------------------------------------
extern "C" void kernel_launch(void* const* d_in, const int* in_sizes, int n_in,
                              void* d_out, int out_size, void* d_ws, size_t ws_size,
                              hipStream_t stream) {
    const float* x     = (const float*)d_in[0];
    // d_in[1] = edge_index (int64) -- unused by the math
    const float* adj   = (const float*)d_in[2];
    const float* W     = (const float*)d_in[3];
    const float* bias  = (const float*)d_in[4];
    const float* alpha = (const float*)d_in[5];
    float* out         = (float*)d_out;

    // Workspace layout
    char* ws = (char*)d_ws;
    size_t off = 0;
    float* xw     = (float*)(ws + off); off += (size_t)NN * FF * sizeof(float);   // 4 MiB
    float* dinv   = (float*)(ws + off); off += (size_t)ORD * NN * sizeof(float);  // 64 KiB
    int*   cnt    = (int*)(ws + off);   off += (size_t)ORD * NN * sizeof(int);    // 64 KiB
    int*   colidx = (int*)(ws + off);   off += (size_t)ORD * NN * CSR_STRIDE * sizeof(int); // 8 MiB
    const int csr_ok = (ws_size >= off) ? 1 : 0;

    hipLaunchKernelGGL(scan_xw_kernel, dim3(XW_BLOCKS + SCAN_BLOCKS), dim3(256), 0, stream,
                       adj, x, W, xw, dinv, cnt, colidx, csr_ok);
    hipLaunchKernelGGL(gather_kernel, dim3(NN), dim3(512), 0, stream,
                       adj, xw, dinv, cnt, colidx, bias, alpha, out, csr_ok);
}

// Round 3
// 129.417 us; speedup vs baseline: 1.5164x; 1.1923x over previous
//
#include <hip/hip_runtime.h>
#include <math.h>

// Problem constants (from reference)
#define NN 8192
#define FF 128
#define ORD 2
#define CSR_STRIDE 128     // per-row column-index capacity; mean nnz ~33, P(>128) ~ 0
#define XW_ROWS 16         // rows per xw-role block
#define XW_BLOCKS (NN / XW_ROWS)      // 512
#define SCAN_BLOCKS (ORD * NN)        // 16384

// ---------------------------------------------------------------------------
// Fused kernel 1: blocks [0, XW_BLOCKS) compute xw = x@W (L2/VALU-bound);
// blocks [XW_BLOCKS, ...) stream-scan adj_powers (HBM-bound). Roles overlap.
// Scan role builds a 32-bit nonzero mask per thread (32 owned columns),
// popcounts for degree, and bit-walks for the CSR write-out: ~half the VALU
// work of the compare-twice version and no float4[8] live across the scan.
// ---------------------------------------------------------------------------
__global__ __launch_bounds__(256) void scan_xw_kernel(
    const float* __restrict__ adj, const float* __restrict__ x,
    const float* __restrict__ W,
    float* __restrict__ xw, float* __restrict__ dinv,
    int* __restrict__ cnt, int* __restrict__ colidx, int csr_ok)
{
    const int t = threadIdx.x;

    if (blockIdx.x < XW_BLOCKS) {
        // ---------------- xw role: 16 rows x 128 cols per block -------------
        const int row0 = blockIdx.x * XW_ROWS;
        __shared__ float xsT[FF * 20];   // x tile transposed, [k][r], stride 20
        for (int idx = t; idx < XW_ROWS * FF; idx += 256) {
            const int r = idx >> 7, k = idx & 127;
            xsT[k * 20 + r] = x[(size_t)(row0 + r) * FF + k];
        }
        __syncthreads();
        const int f = t & 127;
        const int h = t >> 7;            // rows h*8 .. h*8+7
        float acc[8];
#pragma unroll
        for (int r = 0; r < 8; ++r) acc[r] = 0.f;
#pragma unroll 4
        for (int k = 0; k < FF; ++k) {
            const float wk = W[k * FF + f];
            const float4* xp = (const float4*)&xsT[k * 20 + h * 8];
            const float4 a0 = xp[0], a1 = xp[1];
            acc[0] += a0.x * wk; acc[1] += a0.y * wk;
            acc[2] += a0.z * wk; acc[3] += a0.w * wk;
            acc[4] += a1.x * wk; acc[5] += a1.y * wk;
            acc[6] += a1.z * wk; acc[7] += a1.w * wk;
        }
#pragma unroll
        for (int r = 0; r < 8; ++r)
            xw[(size_t)(row0 + h * 8 + r) * FF + f] = acc[r];
        return;
    }

    // ---------------- scan role: one (order,row) per block ------------------
    const int bid = blockIdx.x - XW_BLOCKS;   // o*NN + i
    const int i   = bid & (NN - 1);

    const float4* row = (const float4*)(adj + (size_t)bid * NN);

    // Build nonzero mask: bit (4*s + e) <=> column s*1024 + 4*t + e.
    unsigned int m = 0;
#pragma unroll
    for (int s = 0; s < 8; ++s) {
        const float4 v = row[s * 256 + t];
        if (v.x != 0.f) m |= 1u << (4 * s + 0);
        if (v.y != 0.f) m |= 1u << (4 * s + 1);
        if (v.z != 0.f) m |= 1u << (4 * s + 2);
        if (v.w != 0.f) m |= 1u << (4 * s + 3);
    }
    // Clear the diagonal bit (column i) if this thread owns it.
    if (t == ((i >> 2) & 255)) m &= ~(1u << (((i >> 2) >> 8) * 4 + (i & 3)));

    const int c = __popc(m);

    // Wave-level inclusive scan (wave64), then cross-wave combine: 1 barrier.
    const int lane = t & 63;
    int incl = c;
#pragma unroll
    for (int d = 1; d < 64; d <<= 1) {
        const int n = __shfl_up(incl, d);
        if (lane >= d) incl += n;
    }
    __shared__ int wtot[4];
    if (lane == 63) wtot[t >> 6] = incl;
    __syncthreads();
    const int w = t >> 6;
    int woff = 0;
#pragma unroll
    for (int ww = 0; ww < 3; ++ww)
        if (ww < w) woff += wtot[ww];
    const int total = wtot[0] + wtot[1] + wtot[2] + wtot[3];
    const int myoff = woff + incl - c;        // exclusive prefix, deterministic

    if (t == 0) {
        cnt[bid]  = total;
        dinv[bid] = 1.0f / sqrtf((float)(total + 1));   // deg = total + 1
    }

    if (csr_ok && total <= CSR_STRIDE) {
        int* outp = colidx + (size_t)bid * CSR_STRIDE + myoff;
        unsigned int mm = m;
        const int base = 4 * t;
        while (mm) {
            const int b = __builtin_ctz(mm);
            mm &= mm - 1;
            *outp++ = ((b >> 2) << 10) + base + (b & 3);   // ascending column order
        }
    }
}

// ---------------------------------------------------------------------------
// Kernel 2: gather + combine. One block per output row i, 512 threads =
// 16 groups x 32 lanes; lane l owns features 4l..4l+3 (float4). Both orders
// folded into ONE entry list with pre-scaled weights alpha[o]*di_o*dinv_o[j];
// diagonal collapses to coef*xw[i]. Fixed-order group combine -> deterministic.
// ---------------------------------------------------------------------------
__global__ __launch_bounds__(512) void gather_kernel(
    const float* __restrict__ adj, const float* __restrict__ xw,
    const float* __restrict__ dinv, const int* __restrict__ cnt,
    const int* __restrict__ colidx, const float* __restrict__ bias,
    const float* __restrict__ alpha, float* __restrict__ out, int csr_ok)
{
    const int i = blockIdx.x;
    const int t = threadIdx.x;
    const int l = t & 31;                 // feature block (4 floats)
    const int g = t >> 5;                 // entry group 0..15

    __shared__ int    qj[2 * CSR_STRIDE];
    __shared__ float  qw[2 * CSR_STRIDE];
    __shared__ float4 part[16][32];

    const int   c0 = cnt[i],        c1 = cnt[NN + i];
    const float di0 = dinv[i],      di1 = dinv[NN + i];
    const float a0 = alpha[0],      a1 = alpha[1];
    const int   ctot = c0 + c1;
    const int   fits = csr_ok && (c0 <= CSR_STRIDE) && (c1 <= CSR_STRIDE);

    float4 acc = make_float4(0.f, 0.f, 0.f, 0.f);

    if (fits) {
        if (t < ctot) {
            const int o = (t < c0) ? 0 : 1;
            const int e = (o == 0) ? t : t - c0;
            const int j = colidx[(size_t)(o * NN + i) * CSR_STRIDE + e];
            qj[t] = j;
            qw[t] = ((o == 0) ? a0 * di0 : a1 * di1) * dinv[o * NN + j];
        }
        __syncthreads();
        for (int e = g; e < ctot; e += 16) {
            const int   j = qj[e];
            const float w = qw[e];
            const float4 v = *(const float4*)&xw[(size_t)j * FF + 4 * l];
            acc.x += w * v.x; acc.y += w * v.y;
            acc.z += w * v.z; acc.w += w * v.w;
        }
    } else {
        // Dense fallback (never expected): group g scans columns [g*512,(g+1)*512).
        for (int o = 0; o < ORD; ++o) {
            const float  wo   = (o == 0) ? a0 * di0 : a1 * di1;
            const float* rowp = adj + (size_t)(o * NN + i) * NN;
            for (int j = g * (NN / 16); j < (g + 1) * (NN / 16); ++j) {
                const float a = rowp[j];
                if (a != 0.f && j != i) {
                    const float w = wo * dinv[o * NN + j];
                    const float4 v = *(const float4*)&xw[(size_t)j * FF + 4 * l];
                    acc.x += w * v.x; acc.y += w * v.y;
                    acc.z += w * v.z; acc.w += w * v.w;
                }
            }
        }
    }

    part[g][l] = acc;
    __syncthreads();

    if (t < 32) {
        float4 r = part[0][t];
#pragma unroll
        for (int gg = 1; gg < 16; ++gg) {
            const float4 p = part[gg][t];
            r.x += p.x; r.y += p.y; r.z += p.z; r.w += p.w;
        }
        const float coefd = a0 * di0 * di0 + a1 * di1 * di1;   // diagonal terms
        const float cb    = a0 + a1;                            // bias coefficient
        const float4 xi = *(const float4*)&xw[(size_t)i * FF + 4 * t];
        const float4 bb = *(const float4*)&bias[4 * t];
        r.x += coefd * xi.x + cb * bb.x;
        r.y += coefd * xi.y + cb * bb.y;
        r.z += coefd * xi.z + cb * bb.z;
        r.w += coefd * xi.w + cb * bb.w;
        *(float4*)&out[(size_t)i * FF + 4 * t] = r;
    }
}

// ---------------------------------------------------------------------------
extern "C" void kernel_launch(void* const* d_in, const int* in_sizes, int n_in,
                              void* d_out, int out_size, void* d_ws, size_t ws_size,
                              hipStream_t stream) {
    const float* x     = (const float*)d_in[0];
    // d_in[1] = edge_index (int64) -- unused by the math
    const float* adj   = (const float*)d_in[2];
    const float* W     = (const float*)d_in[3];
    const float* bias  = (const float*)d_in[4];
    const float* alpha = (const float*)d_in[5];
    float* out         = (float*)d_out;

    // Workspace layout
    char* ws = (char*)d_ws;
    size_t off = 0;
    float* xw     = (float*)(ws + off); off += (size_t)NN * FF * sizeof(float);   // 4 MiB
    float* dinv   = (float*)(ws + off); off += (size_t)ORD * NN * sizeof(float);  // 64 KiB
    int*   cnt    = (int*)(ws + off);   off += (size_t)ORD * NN * sizeof(int);    // 64 KiB
    int*   colidx = (int*)(ws + off);   off += (size_t)ORD * NN * CSR_STRIDE * sizeof(int); // 8 MiB
    const int csr_ok = (ws_size >= off) ? 1 : 0;

    hipLaunchKernelGGL(scan_xw_kernel, dim3(XW_BLOCKS + SCAN_BLOCKS), dim3(256), 0, stream,
                       adj, x, W, xw, dinv, cnt, colidx, csr_ok);
    hipLaunchKernelGGL(gather_kernel, dim3(NN), dim3(512), 0, stream,
                       adj, xw, dinv, cnt, colidx, bias, alpha, out, csr_ok);
}

// Round 4
// 128.177 us; speedup vs baseline: 1.5311x; 1.0097x over previous
//
#include <hip/hip_runtime.h>
#include <math.h>

// Problem constants (from reference)
#define NN 8192
#define FF 128
#define ORD 2
#define CSR_STRIDE 128     // per-row column-index capacity; mean nnz ~33, P(>128) ~ 0
#define XW_ROWS 16         // rows per xw-role block
#define XW_BLOCKS (NN / XW_ROWS)      // 512

// bf16 RNE encode / exact decode (bf16 = top 16 bits of f32)
__device__ __forceinline__ unsigned short f2bf(float v) {
    const unsigned int u = __float_as_uint(v);
    return (unsigned short)((u + 0x7FFFu + ((u >> 16) & 1u)) >> 16);
}
__device__ __forceinline__ float bf2f(unsigned short h) {
    return __uint_as_float((unsigned int)h << 16);
}

// ---------------------------------------------------------------------------
// Kernel A: blocks [0, XW_BLOCKS) compute xw = x@W (f32 + bf16 copy);
// blocks [XW_BLOCKS, XW_BLOCKS+NN) stream-scan adj_powers ORDER 0.
// Scan: 32-bit nonzero mask per thread, popc degree, bit-walk CSR write.
// ---------------------------------------------------------------------------
__global__ __launch_bounds__(256) void kernelA(
    const float* __restrict__ adj, const float* __restrict__ x,
    const float* __restrict__ W,
    float* __restrict__ xw, unsigned short* __restrict__ xwh,
    float* __restrict__ dinv, int* __restrict__ cnt,
    int* __restrict__ colidx, int csr_ok)
{
    const int t = threadIdx.x;

    if (blockIdx.x < XW_BLOCKS) {
        // ---------------- xw role: 16 rows x 128 cols per block -------------
        const int row0 = blockIdx.x * XW_ROWS;
        __shared__ float xsT[FF * 20];   // x tile transposed, [k][r], stride 20
        for (int idx = t; idx < XW_ROWS * FF; idx += 256) {
            const int r = idx >> 7, k = idx & 127;
            xsT[k * 20 + r] = x[(size_t)(row0 + r) * FF + k];
        }
        __syncthreads();
        const int f = t & 127;
        const int h = t >> 7;            // rows h*8 .. h*8+7
        float acc[8];
#pragma unroll
        for (int r = 0; r < 8; ++r) acc[r] = 0.f;
#pragma unroll 4
        for (int k = 0; k < FF; ++k) {
            const float wk = W[k * FF + f];
            const float4* xp = (const float4*)&xsT[k * 20 + h * 8];
            const float4 a0 = xp[0], a1 = xp[1];
            acc[0] += a0.x * wk; acc[1] += a0.y * wk;
            acc[2] += a0.z * wk; acc[3] += a0.w * wk;
            acc[4] += a1.x * wk; acc[5] += a1.y * wk;
            acc[6] += a1.z * wk; acc[7] += a1.w * wk;
        }
#pragma unroll
        for (int r = 0; r < 8; ++r) {
            const size_t idx = (size_t)(row0 + h * 8 + r) * FF + f;
            xw[idx]  = acc[r];
            xwh[idx] = f2bf(acc[r]);
        }
        return;
    }

    // ---------------- scan role: order 0, one row per block -----------------
    const int i = blockIdx.x - XW_BLOCKS;

    const float4* row = (const float4*)(adj + (size_t)i * NN);

    unsigned int m = 0;
#pragma unroll
    for (int s = 0; s < 8; ++s) {
        const float4 v = row[s * 256 + t];
        if (v.x != 0.f) m |= 1u << (4 * s + 0);
        if (v.y != 0.f) m |= 1u << (4 * s + 1);
        if (v.z != 0.f) m |= 1u << (4 * s + 2);
        if (v.w != 0.f) m |= 1u << (4 * s + 3);
    }
    if (t == ((i >> 2) & 255)) m &= ~(1u << ((i >> 10) * 4 + (i & 3)));

    const int c = __popc(m);

    const int lane = t & 63;
    int incl = c;
#pragma unroll
    for (int d = 1; d < 64; d <<= 1) {
        const int n = __shfl_up(incl, d);
        if (lane >= d) incl += n;
    }
    __shared__ int wtot[4];
    if (lane == 63) wtot[t >> 6] = incl;
    __syncthreads();
    const int w = t >> 6;
    int woff = 0;
#pragma unroll
    for (int ww = 0; ww < 3; ++ww)
        if (ww < w) woff += wtot[ww];
    const int total = wtot[0] + wtot[1] + wtot[2] + wtot[3];
    const int myoff = woff + incl - c;

    if (t == 0) {
        cnt[i]  = total;
        dinv[i] = 1.0f / sqrtf((float)(total + 1));
    }

    if (csr_ok && total <= CSR_STRIDE) {
        int* outp = colidx + (size_t)i * CSR_STRIDE + myoff;
        unsigned int mm = m;
        const int base = 4 * t;
        while (mm) {
            const int b = __builtin_ctz(mm);
            mm &= mm - 1;
            *outp++ = ((b >> 2) << 10) + base + (b & 3);
        }
    }
}

// ---------------------------------------------------------------------------
// Kernel B: even blocks scan order 1 (HBM-bound); odd blocks gather order 0
// (L2/L3-bound) using order-0 CSR from kernel A. The two roles overlap.
// Gather: 8 groups x 32 lanes, bf16 xw rows (8 B/lane), weights pre-scaled
// by alpha0*di0*dinv0[j]; partial (incl. diagonal) written to ws as f32.
// ---------------------------------------------------------------------------
__global__ __launch_bounds__(256) void kernelB(
    const float* __restrict__ adj, const float* __restrict__ xw,
    const unsigned short* __restrict__ xwh,
    float* __restrict__ dinv, int* __restrict__ cnt,
    int* __restrict__ colidx, const float* __restrict__ alpha,
    float* __restrict__ partial, int csr_ok)
{
    const int t = threadIdx.x;
    const int bid = blockIdx.x;

    if ((bid & 1) == 0) {
        // ---------------- scan role: order 1, row = bid>>1 ------------------
        const int i = bid >> 1;
        const float4* row = (const float4*)(adj + (size_t)(NN + i) * NN);

        unsigned int m = 0;
#pragma unroll
        for (int s = 0; s < 8; ++s) {
            const float4 v = row[s * 256 + t];
            if (v.x != 0.f) m |= 1u << (4 * s + 0);
            if (v.y != 0.f) m |= 1u << (4 * s + 1);
            if (v.z != 0.f) m |= 1u << (4 * s + 2);
            if (v.w != 0.f) m |= 1u << (4 * s + 3);
        }
        if (t == ((i >> 2) & 255)) m &= ~(1u << ((i >> 10) * 4 + (i & 3)));

        const int c = __popc(m);

        const int lane = t & 63;
        int incl = c;
#pragma unroll
        for (int d = 1; d < 64; d <<= 1) {
            const int n = __shfl_up(incl, d);
            if (lane >= d) incl += n;
        }
        __shared__ int wtot[4];
        if (lane == 63) wtot[t >> 6] = incl;
        __syncthreads();
        const int w = t >> 6;
        int woff = 0;
#pragma unroll
        for (int ww = 0; ww < 3; ++ww)
            if (ww < w) woff += wtot[ww];
        const int total = wtot[0] + wtot[1] + wtot[2] + wtot[3];
        const int myoff = woff + incl - c;

        if (t == 0) {
            cnt[NN + i]  = total;
            dinv[NN + i] = 1.0f / sqrtf((float)(total + 1));
        }

        if (csr_ok && total <= CSR_STRIDE) {
            int* outp = colidx + (size_t)(NN + i) * CSR_STRIDE + myoff;
            unsigned int mm = m;
            const int base = 4 * t;
            while (mm) {
                const int b = __builtin_ctz(mm);
                mm &= mm - 1;
                *outp++ = ((b >> 2) << 10) + base + (b & 3);
            }
        }
        return;
    }

    // ---------------- gather role: order 0, row i = bid>>1 ------------------
    const int i = bid >> 1;
    const int l = t & 31;                 // feature block (4 floats)
    const int g = t >> 5;                 // entry group 0..7

    __shared__ int    qj[CSR_STRIDE];
    __shared__ float  qw[CSR_STRIDE];
    __shared__ float4 part[8][32];

    const int   c0  = cnt[i];
    const float di0 = dinv[i];
    const float a0  = alpha[0];

    float4 acc = make_float4(0.f, 0.f, 0.f, 0.f);

    if (csr_ok && c0 <= CSR_STRIDE) {
        if (t < c0) {
            const int j = colidx[(size_t)i * CSR_STRIDE + t];
            qj[t] = j;
            qw[t] = a0 * di0 * dinv[j];
        }
        __syncthreads();
        for (int e = g; e < c0; e += 8) {
            const int   j = qj[e];
            const float w = qw[e];
            const ushort4 hv = *(const ushort4*)&xwh[(size_t)j * FF + 4 * l];
            acc.x += w * bf2f(hv.x); acc.y += w * bf2f(hv.y);
            acc.z += w * bf2f(hv.z); acc.w += w * bf2f(hv.w);
        }
    } else {
        // Dense fallback (never expected): group g scans its column range.
        const float* rowp = adj + (size_t)i * NN;
        for (int j = g * (NN / 8); j < (g + 1) * (NN / 8); ++j) {
            const float a = rowp[j];
            if (a != 0.f && j != i) {
                const float w = a0 * di0 * dinv[j];
                const float4 v = *(const float4*)&xw[(size_t)j * FF + 4 * l];
                acc.x += w * v.x; acc.y += w * v.y;
                acc.z += w * v.z; acc.w += w * v.w;
            }
        }
    }

    part[g][l] = acc;
    __syncthreads();

    if (t < 32) {
        float4 r = part[0][t];
#pragma unroll
        for (int gg = 1; gg < 8; ++gg) {
            const float4 p = part[gg][t];
            r.x += p.x; r.y += p.y; r.z += p.z; r.w += p.w;
        }
        const float coefd = a0 * di0 * di0;   // order-0 diagonal (exact f32 xw)
        const float4 xi = *(const float4*)&xw[(size_t)i * FF + 4 * t];
        r.x += coefd * xi.x; r.y += coefd * xi.y;
        r.z += coefd * xi.z; r.w += coefd * xi.w;
        *(float4*)&partial[(size_t)i * FF + 4 * t] = r;
    }
}

// ---------------------------------------------------------------------------
// Kernel C: gather order 1 + combine: out = partial + gather1 + diag1 + bias.
// ---------------------------------------------------------------------------
__global__ __launch_bounds__(256) void kernelC(
    const float* __restrict__ adj, const float* __restrict__ xw,
    const unsigned short* __restrict__ xwh,
    const float* __restrict__ dinv, const int* __restrict__ cnt,
    const int* __restrict__ colidx, const float* __restrict__ bias,
    const float* __restrict__ alpha, const float* __restrict__ partial,
    float* __restrict__ out, int csr_ok)
{
    const int i = blockIdx.x;
    const int t = threadIdx.x;
    const int l = t & 31;
    const int g = t >> 5;

    __shared__ int    qj[CSR_STRIDE];
    __shared__ float  qw[CSR_STRIDE];
    __shared__ float4 part[8][32];

    const int   c1  = cnt[NN + i];
    const float di1 = dinv[NN + i];
    const float a0  = alpha[0], a1 = alpha[1];

    float4 acc = make_float4(0.f, 0.f, 0.f, 0.f);

    if (csr_ok && c1 <= CSR_STRIDE) {
        if (t < c1) {
            const int j = colidx[(size_t)(NN + i) * CSR_STRIDE + t];
            qj[t] = j;
            qw[t] = a1 * di1 * dinv[NN + j];
        }
        __syncthreads();
        for (int e = g; e < c1; e += 8) {
            const int   j = qj[e];
            const float w = qw[e];
            const ushort4 hv = *(const ushort4*)&xwh[(size_t)j * FF + 4 * l];
            acc.x += w * bf2f(hv.x); acc.y += w * bf2f(hv.y);
            acc.z += w * bf2f(hv.z); acc.w += w * bf2f(hv.w);
        }
    } else {
        const float* rowp = adj + (size_t)(NN + i) * NN;
        for (int j = g * (NN / 8); j < (g + 1) * (NN / 8); ++j) {
            const float a = rowp[j];
            if (a != 0.f && j != i) {
                const float w = a1 * di1 * dinv[NN + j];
                const float4 v = *(const float4*)&xw[(size_t)j * FF + 4 * l];
                acc.x += w * v.x; acc.y += w * v.y;
                acc.z += w * v.z; acc.w += w * v.w;
            }
        }
    }

    part[g][l] = acc;
    __syncthreads();

    if (t < 32) {
        float4 r = part[0][t];
#pragma unroll
        for (int gg = 1; gg < 8; ++gg) {
            const float4 p = part[gg][t];
            r.x += p.x; r.y += p.y; r.z += p.z; r.w += p.w;
        }
        const float coefd = a1 * di1 * di1;   // order-1 diagonal
        const float cb    = a0 + a1;          // bias coefficient
        const float4 xi = *(const float4*)&xw[(size_t)i * FF + 4 * t];
        const float4 bb = *(const float4*)&bias[4 * t];
        const float4 pp = *(const float4*)&partial[(size_t)i * FF + 4 * t];
        r.x += pp.x + coefd * xi.x + cb * bb.x;
        r.y += pp.y + coefd * xi.y + cb * bb.y;
        r.z += pp.z + coefd * xi.z + cb * bb.z;
        r.w += pp.w + coefd * xi.w + cb * bb.w;
        *(float4*)&out[(size_t)i * FF + 4 * t] = r;
    }
}

// ---------------------------------------------------------------------------
extern "C" void kernel_launch(void* const* d_in, const int* in_sizes, int n_in,
                              void* d_out, int out_size, void* d_ws, size_t ws_size,
                              hipStream_t stream) {
    const float* x     = (const float*)d_in[0];
    // d_in[1] = edge_index (int64) -- unused by the math
    const float* adj   = (const float*)d_in[2];
    const float* W     = (const float*)d_in[3];
    const float* bias  = (const float*)d_in[4];
    const float* alpha = (const float*)d_in[5];
    float* out         = (float*)d_out;

    // Workspace layout
    char* ws = (char*)d_ws;
    size_t off = 0;
    float*          xw      = (float*)(ws + off); off += (size_t)NN * FF * sizeof(float);          // 4 MiB
    unsigned short* xwh     = (unsigned short*)(ws + off); off += (size_t)NN * FF * sizeof(short); // 2 MiB
    float*          dinv    = (float*)(ws + off); off += (size_t)ORD * NN * sizeof(float);         // 64 KiB
    int*            cnt     = (int*)(ws + off);   off += (size_t)ORD * NN * sizeof(int);           // 64 KiB
    int*            colidx  = (int*)(ws + off);   off += (size_t)ORD * NN * CSR_STRIDE * sizeof(int); // 8 MiB
    float*          partial = (float*)(ws + off); off += (size_t)NN * FF * sizeof(float);          // 4 MiB
    const int csr_ok = (ws_size >= off) ? 1 : 0;

    hipLaunchKernelGGL(kernelA, dim3(XW_BLOCKS + NN), dim3(256), 0, stream,
                       adj, x, W, xw, xwh, dinv, cnt, colidx, csr_ok);
    hipLaunchKernelGGL(kernelB, dim3(2 * NN), dim3(256), 0, stream,
                       adj, xw, xwh, dinv, cnt, colidx, alpha, partial, csr_ok);
    hipLaunchKernelGGL(kernelC, dim3(NN), dim3(256), 0, stream,
                       adj, xw, xwh, dinv, cnt, colidx, bias, alpha, partial, out, csr_ok);
}

// Round 5
// 125.481 us; speedup vs baseline: 1.5640x; 1.0215x over previous
//
#include <hip/hip_runtime.h>
#include <math.h>

// Problem constants (from reference)
#define NN 8192
#define FF 128
#define ORD 2
#define CSR_STRIDE 128     // per-row column-index capacity; mean nnz ~33, P(>128) ~ 0
#define XW_ROWS 16         // rows per xw-role block
#define XW_BLOCKS (NN / XW_ROWS)      // 512
#define SCAN_BLOCKS 1024              // 4 waves/block
#define ROWS_PER_WAVE 4
#define NWAVES (SCAN_BLOCKS * 4)      // 4096 waves x 4 rows = 16384 rows

// bf16 RNE encode / exact decode (bf16 = top 16 bits of f32)
__device__ __forceinline__ unsigned short f2bf(float v) {
    const unsigned int u = __float_as_uint(v);
    return (unsigned short)((u + 0x7FFFu + ((u >> 16) & 1u)) >> 16);
}
__device__ __forceinline__ float bflo(unsigned int u) { return __uint_as_float(u << 16); }
__device__ __forceinline__ float bfhi(unsigned int u) { return __uint_as_float(u & 0xFFFF0000u); }

// ---------------------------------------------------------------------------
// Kernel A: blocks [0, XW_BLOCKS) compute xw = x@W (f32 + bf16 copy);
// blocks [XW_BLOCKS, XW_BLOCKS+SCAN_BLOCKS) scan BOTH orders of adj_powers.
// Scan is WAVE-AUTONOMOUS: each 64-lane wave owns full rows (32 float4/lane
// in 4 chunks), builds 4x32-bit nonzero masks, popc degree, __shfl_up wave
// prefix scan, bit-walk CSR write. No LDS, no __syncthreads in the scan path
// -> nothing impedes load issue across rows; minimal block churn.
// ---------------------------------------------------------------------------
__global__ __launch_bounds__(256) void kernelA(
    const float* __restrict__ adj, const float* __restrict__ x,
    const float* __restrict__ W,
    float* __restrict__ xw, unsigned short* __restrict__ xwh,
    float* __restrict__ dinv, int* __restrict__ cnt,
    int* __restrict__ colidx, int csr_ok)
{
    const int t = threadIdx.x;

    if (blockIdx.x < XW_BLOCKS) {
        // ---------------- xw role: 16 rows x 128 cols per block -------------
        const int row0 = blockIdx.x * XW_ROWS;
        __shared__ float xsT[FF * 20];   // x tile transposed, [k][r], stride 20
        for (int idx = t; idx < XW_ROWS * FF; idx += 256) {
            const int r = idx >> 7, k = idx & 127;
            xsT[k * 20 + r] = x[(size_t)(row0 + r) * FF + k];
        }
        __syncthreads();
        const int f = t & 127;
        const int h = t >> 7;            // rows h*8 .. h*8+7
        float acc[8];
#pragma unroll
        for (int r = 0; r < 8; ++r) acc[r] = 0.f;
#pragma unroll 4
        for (int k = 0; k < FF; ++k) {
            const float wk = W[k * FF + f];
            const float4* xp = (const float4*)&xsT[k * 20 + h * 8];
            const float4 a0 = xp[0], a1 = xp[1];
            acc[0] += a0.x * wk; acc[1] += a0.y * wk;
            acc[2] += a0.z * wk; acc[3] += a0.w * wk;
            acc[4] += a1.x * wk; acc[5] += a1.y * wk;
            acc[6] += a1.z * wk; acc[7] += a1.w * wk;
        }
#pragma unroll
        for (int r = 0; r < 8; ++r) {
            const size_t idx = (size_t)(row0 + h * 8 + r) * FF + f;
            xw[idx]  = acc[r];
            xwh[idx] = f2bf(acc[r]);
        }
        return;
    }

    // ---------------- scan role: wave-autonomous rows ----------------------
    const int wave_id = (blockIdx.x - XW_BLOCKS) * 4 + (t >> 6);
    const int lane = t & 63;
    const int b4l  = 4 * lane;

#pragma unroll 1
    for (int k = 0; k < ROWS_PER_WAVE; ++k) {
        const int r = k * NWAVES + wave_id;   // global row 0..16383 (o = r>>13)
        const int i = r & (NN - 1);
        const float4* rowp = (const float4*)(adj + (size_t)r * NN);

        // 4 chunks x 8 float4 per lane; mask bit (4s+e) <=> col ch*2048+s*256+4*lane+e
        unsigned int m[4];
#pragma unroll
        for (int ch = 0; ch < 4; ++ch) {
            float4 v[8];
#pragma unroll
            for (int s = 0; s < 8; ++s) v[s] = rowp[ch * 512 + s * 64 + lane];
            unsigned int mm = 0;
#pragma unroll
            for (int s = 0; s < 8; ++s) {
                if (v[s].x != 0.f) mm |= 1u << (4 * s + 0);
                if (v[s].y != 0.f) mm |= 1u << (4 * s + 1);
                if (v[s].z != 0.f) mm |= 1u << (4 * s + 2);
                if (v[s].w != 0.f) mm |= 1u << (4 * s + 3);
            }
            m[ch] = mm;
        }

        // Clear the diagonal bit (column i). Static indexing into m[] only.
        {
            const int p_i    = i >> 2;
            const int lane_i = p_i & 63;
            const int ch_i   = p_i >> 9;
            const unsigned int bit = 1u << (4 * ((p_i >> 6) & 7) + (i & 3));
#pragma unroll
            for (int ch = 0; ch < 4; ++ch)
                if (ch == ch_i && lane == lane_i) m[ch] &= ~bit;
        }

        const int c = __popc(m[0]) + __popc(m[1]) + __popc(m[2]) + __popc(m[3]);

        // Wave-level inclusive prefix scan — no LDS, no barrier.
        int incl = c;
#pragma unroll
        for (int d = 1; d < 64; d <<= 1) {
            const int n = __shfl_up(incl, d);
            if (lane >= d) incl += n;
        }
        const int total = __shfl(incl, 63);

        if (lane == 0) {
            cnt[r]  = total;
            dinv[r] = 1.0f / sqrtf((float)(total + 1));   // deg = total + 1
        }

        if (csr_ok && total <= CSR_STRIDE) {
            int* outp = colidx + (size_t)r * CSR_STRIDE + (incl - c);
#pragma unroll
            for (int ch = 0; ch < 4; ++ch) {
                unsigned int mm = m[ch];
                while (mm) {
                    const int bq = __builtin_ctz(mm);
                    mm &= mm - 1;
                    *outp++ = ch * 2048 + ((bq >> 2) << 8) + b4l + (bq & 3);
                }
            }
        }
    }
}

// ---------------------------------------------------------------------------
// Kernel B: gather both orders + combine. One block per output row i,
// 256 threads = 16 groups x 16 lanes; lane fb owns features 8fb..8fb+7
// (one uint4 = 8 bf16 per row read -> full 256B/wave). Both orders folded
// into one entry list with pre-scaled weights; diagonal uses exact f32 xw.
// Fixed tree combine -> deterministic FP order.
// ---------------------------------------------------------------------------
__global__ __launch_bounds__(256) void kernelB(
    const float* __restrict__ adj, const float* __restrict__ xw,
    const unsigned short* __restrict__ xwh,
    const float* __restrict__ dinv, const int* __restrict__ cnt,
    const int* __restrict__ colidx, const float* __restrict__ bias,
    const float* __restrict__ alpha, float* __restrict__ out, int csr_ok)
{
    const int i  = blockIdx.x;
    const int t  = threadIdx.x;
    const int fb = t & 15;       // feature block (8 floats)
    const int g  = t >> 4;       // entry group 0..15

    __shared__ int   qj[2 * CSR_STRIDE];
    __shared__ float qw[2 * CSR_STRIDE];
    __shared__ float part[16][16][8];

    const int   c0  = cnt[i],  c1  = cnt[NN + i];
    const float di0 = dinv[i], di1 = dinv[NN + i];
    const float a0  = alpha[0], a1 = alpha[1];
    const int   ctot = c0 + c1;
    const int   fits = csr_ok && (c0 <= CSR_STRIDE) && (c1 <= CSR_STRIDE);

    float acc[8];
#pragma unroll
    for (int c = 0; c < 8; ++c) acc[c] = 0.f;

    if (fits) {
        if (t < ctot) {
            const int o = (t < c0) ? 0 : 1;
            const int e = (o == 0) ? t : t - c0;
            const int j = colidx[(size_t)(o * NN + i) * CSR_STRIDE + e];
            qj[t] = j;
            qw[t] = ((o == 0) ? a0 * di0 : a1 * di1) * dinv[o * NN + j];
        }
        __syncthreads();
        for (int e = g; e < ctot; e += 16) {
            const int   j = qj[e];
            const float w = qw[e];
            const uint4 u = *(const uint4*)&xwh[(size_t)j * FF + 8 * fb];
            acc[0] += w * bflo(u.x); acc[1] += w * bfhi(u.x);
            acc[2] += w * bflo(u.y); acc[3] += w * bfhi(u.y);
            acc[4] += w * bflo(u.z); acc[5] += w * bfhi(u.z);
            acc[6] += w * bflo(u.w); acc[7] += w * bfhi(u.w);
        }
    } else {
        // Dense fallback (never expected): group g scans its column range.
        for (int o = 0; o < ORD; ++o) {
            const float  wo   = (o == 0) ? a0 * di0 : a1 * di1;
            const float* rowp = adj + (size_t)(o * NN + i) * NN;
            for (int j = g * (NN / 16); j < (g + 1) * (NN / 16); ++j) {
                const float a = rowp[j];
                if (a != 0.f && j != i) {
                    const float w = wo * dinv[o * NN + j];
                    const float* xr = &xw[(size_t)j * FF + 8 * fb];
#pragma unroll
                    for (int c = 0; c < 8; ++c) acc[c] += w * xr[c];
                }
            }
        }
    }

#pragma unroll
    for (int c = 0; c < 8; ++c) part[g][fb][c] = acc[c];
    __syncthreads();

    // Fixed binary-tree combine over the 16 groups (deterministic).
#pragma unroll
    for (int step = 8; step >= 1; step >>= 1) {
        if (g < step) {
#pragma unroll
            for (int c = 0; c < 8; ++c) part[g][fb][c] += part[g + step][fb][c];
        }
        __syncthreads();
    }

    if (t < 16) {
        const float coefd = a0 * di0 * di0 + a1 * di1 * di1;   // diagonal terms
        const float cb    = a0 + a1;                            // bias coefficient
        const float* xi = &xw[(size_t)i * FF + 8 * t];
        const float* bb = &bias[8 * t];
        float r[8];
#pragma unroll
        for (int c = 0; c < 8; ++c)
            r[c] = part[0][t][c] + coefd * xi[c] + cb * bb[c];
        *(float4*)&out[(size_t)i * FF + 8 * t]     = make_float4(r[0], r[1], r[2], r[3]);
        *(float4*)&out[(size_t)i * FF + 8 * t + 4] = make_float4(r[4], r[5], r[6], r[7]);
    }
}

// ---------------------------------------------------------------------------
extern "C" void kernel_launch(void* const* d_in, const int* in_sizes, int n_in,
                              void* d_out, int out_size, void* d_ws, size_t ws_size,
                              hipStream_t stream) {
    const float* x     = (const float*)d_in[0];
    // d_in[1] = edge_index (int64) -- unused by the math
    const float* adj   = (const float*)d_in[2];
    const float* W     = (const float*)d_in[3];
    const float* bias  = (const float*)d_in[4];
    const float* alpha = (const float*)d_in[5];
    float* out         = (float*)d_out;

    // Workspace layout
    char* ws = (char*)d_ws;
    size_t off = 0;
    float*          xw     = (float*)(ws + off); off += (size_t)NN * FF * sizeof(float);          // 4 MiB
    unsigned short* xwh    = (unsigned short*)(ws + off); off += (size_t)NN * FF * sizeof(short); // 2 MiB
    float*          dinv   = (float*)(ws + off); off += (size_t)ORD * NN * sizeof(float);         // 64 KiB
    int*            cnt    = (int*)(ws + off);   off += (size_t)ORD * NN * sizeof(int);           // 64 KiB
    int*            colidx = (int*)(ws + off);   off += (size_t)ORD * NN * CSR_STRIDE * sizeof(int); // 8 MiB
    const int csr_ok = (ws_size >= off) ? 1 : 0;

    hipLaunchKernelGGL(kernelA, dim3(XW_BLOCKS + SCAN_BLOCKS), dim3(256), 0, stream,
                       adj, x, W, xw, xwh, dinv, cnt, colidx, csr_ok);
    hipLaunchKernelGGL(kernelB, dim3(NN), dim3(256), 0, stream,
                       adj, xw, xwh, dinv, cnt, colidx, bias, alpha, out, csr_ok);
}

// Round 6
// 112.939 us; speedup vs baseline: 1.7377x; 1.1110x over previous
//
#include <hip/hip_runtime.h>
#include <math.h>

// Problem constants (from reference)
#define NN 8192
#define FF 128
#define ORD 2
#define CSR_STRIDE 128     // per-row column-index capacity; mean nnz ~33, P(>128) ~ 0
#define XW_ROWS 16         // rows per xw-role block
#define XW_BLOCKS (NN / XW_ROWS)      // 512
#define SCAN_BLOCKS 1024              // 4 waves/block
#define ROWS_PER_WAVE 4
#define NWAVES (SCAN_BLOCKS * 4)      // 4096 waves x 4 rows = 16384 rows

typedef float __attribute__((ext_vector_type(4))) f4;

// bf16 RNE encode / exact decode (bf16 = top 16 bits of f32)
__device__ __forceinline__ unsigned short f2bf(float v) {
    const unsigned int u = __float_as_uint(v);
    return (unsigned short)((u + 0x7FFFu + ((u >> 16) & 1u)) >> 16);
}
__device__ __forceinline__ float bflo(unsigned int u) { return __uint_as_float(u << 16); }
__device__ __forceinline__ float bfhi(unsigned int u) { return __uint_as_float(u & 0xFFFF0000u); }

// ---------------------------------------------------------------------------
// Kernel A: blocks [0, SCAN_BLOCKS) scan BOTH orders (wave-autonomous, no LDS,
// no barriers); blocks [SCAN_BLOCKS, +XW_BLOCKS) compute xw = x@W at the TAIL
// of the grid so the scan saturates HBM from t=0.
// Scan per row: nontemporal (nt) float4 loads, explicit 2-deep register
// double-buffer across the 4 chunks (8 loads always in flight -> counted
// vmcnt, no full drain per chunk), 4x32-bit masks, popc, __shfl_up scan,
// bit-walk CSR write.
// ---------------------------------------------------------------------------
__global__ __launch_bounds__(256) void kernelA(
    const float* __restrict__ adj, const float* __restrict__ x,
    const float* __restrict__ W,
    float* __restrict__ xw, unsigned short* __restrict__ xwh,
    float* __restrict__ dinv, int* __restrict__ cnt,
    int* __restrict__ colidx, int csr_ok)
{
    const int t = threadIdx.x;

    if (blockIdx.x >= SCAN_BLOCKS) {
        // ---------------- xw role: 16 rows x 128 cols per block -------------
        const int row0 = (blockIdx.x - SCAN_BLOCKS) * XW_ROWS;
        __shared__ float xsT[FF * 20];   // x tile transposed, [k][r], stride 20
        for (int idx = t; idx < XW_ROWS * FF; idx += 256) {
            const int r = idx >> 7, k = idx & 127;
            xsT[k * 20 + r] = x[(size_t)(row0 + r) * FF + k];
        }
        __syncthreads();
        const int f = t & 127;
        const int h = t >> 7;            // rows h*8 .. h*8+7
        float acc[8];
#pragma unroll
        for (int r = 0; r < 8; ++r) acc[r] = 0.f;
#pragma unroll 4
        for (int k = 0; k < FF; ++k) {
            const float wk = W[k * FF + f];
            const float4* xp = (const float4*)&xsT[k * 20 + h * 8];
            const float4 a0 = xp[0], a1 = xp[1];
            acc[0] += a0.x * wk; acc[1] += a0.y * wk;
            acc[2] += a0.z * wk; acc[3] += a0.w * wk;
            acc[4] += a1.x * wk; acc[5] += a1.y * wk;
            acc[6] += a1.z * wk; acc[7] += a1.w * wk;
        }
#pragma unroll
        for (int r = 0; r < 8; ++r) {
            const size_t idx = (size_t)(row0 + h * 8 + r) * FF + f;
            xw[idx]  = acc[r];
            xwh[idx] = f2bf(acc[r]);
        }
        return;
    }

    // ---------------- scan role: wave-autonomous rows ----------------------
    const int wave_id = blockIdx.x * 4 + (t >> 6);
    const int lane = t & 63;
    const int b4l  = 4 * lane;

#pragma unroll 1
    for (int k = 0; k < ROWS_PER_WAVE; ++k) {
        const int r = k * NWAVES + wave_id;   // global row 0..16383 (o = r>>13)
        const int i = r & (NN - 1);
        const f4* rowp = (const f4*)(adj + (size_t)r * NN);

        f4 v0[8], v1[8];
        // Prologue: chunk 0 loads (nt).
#pragma unroll
        for (int s = 0; s < 8; ++s)
            v0[s] = __builtin_nontemporal_load(rowp + s * 64 + lane);

        unsigned int m[4];
#pragma unroll
        for (int ch = 0; ch < 4; ++ch) {
            f4* cur = (ch & 1) ? v1 : v0;
            f4* nxt = (ch & 1) ? v0 : v1;
            if (ch < 3) {
#pragma unroll
                for (int s = 0; s < 8; ++s)
                    nxt[s] = __builtin_nontemporal_load(rowp + (ch + 1) * 512 + s * 64 + lane);
            }
            unsigned int mm = 0;
#pragma unroll
            for (int s = 0; s < 8; ++s) {
                const f4 vv = cur[s];
#pragma unroll
                for (int e = 0; e < 4; ++e)
                    if (vv[e] != 0.f) mm |= 1u << (4 * s + e);
            }
            m[ch] = mm;
        }

        // Clear the diagonal bit (column i). Static indexing into m[] only.
        {
            const int p_i    = i >> 2;
            const int lane_i = p_i & 63;
            const int ch_i   = p_i >> 9;
            const unsigned int bit = 1u << (4 * ((p_i >> 6) & 7) + (i & 3));
#pragma unroll
            for (int ch = 0; ch < 4; ++ch)
                if (ch == ch_i && lane == lane_i) m[ch] &= ~bit;
        }

        const int c = __popc(m[0]) + __popc(m[1]) + __popc(m[2]) + __popc(m[3]);

        // Wave-level inclusive prefix scan — no LDS, no barrier.
        int incl = c;
#pragma unroll
        for (int d = 1; d < 64; d <<= 1) {
            const int n = __shfl_up(incl, d);
            if (lane >= d) incl += n;
        }
        const int total = __shfl(incl, 63);

        if (lane == 0) {
            cnt[r]  = total;
            dinv[r] = 1.0f / sqrtf((float)(total + 1));   // deg = total + 1
        }

        if (csr_ok && total <= CSR_STRIDE) {
            int* outp = colidx + (size_t)r * CSR_STRIDE + (incl - c);
#pragma unroll
            for (int ch = 0; ch < 4; ++ch) {
                unsigned int mm = m[ch];
                while (mm) {
                    const int bq = __builtin_ctz(mm);
                    mm &= mm - 1;
                    *outp++ = ch * 2048 + ((bq >> 2) << 8) + b4l + (bq & 3);
                }
            }
        }
    }
}

// ---------------------------------------------------------------------------
// Kernel B: gather both orders + combine. One block per output row i,
// 256 threads = 16 groups x 16 lanes; lane fb owns features 8fb..8fb+7
// (one uint4 = 8 bf16 per row read -> full 256B/wave). Both orders folded
// into one entry list with pre-scaled weights; diagonal uses exact f32 xw.
// Fixed tree combine -> deterministic FP order.
// ---------------------------------------------------------------------------
__global__ __launch_bounds__(256) void kernelB(
    const float* __restrict__ adj, const float* __restrict__ xw,
    const unsigned short* __restrict__ xwh,
    const float* __restrict__ dinv, const int* __restrict__ cnt,
    const int* __restrict__ colidx, const float* __restrict__ bias,
    const float* __restrict__ alpha, float* __restrict__ out, int csr_ok)
{
    const int i  = blockIdx.x;
    const int t  = threadIdx.x;
    const int fb = t & 15;       // feature block (8 floats)
    const int g  = t >> 4;       // entry group 0..15

    __shared__ int   qj[2 * CSR_STRIDE];
    __shared__ float qw[2 * CSR_STRIDE];
    __shared__ float part[16][16][8];

    const int   c0  = cnt[i],  c1  = cnt[NN + i];
    const float di0 = dinv[i], di1 = dinv[NN + i];
    const float a0  = alpha[0], a1 = alpha[1];
    const int   ctot = c0 + c1;
    const int   fits = csr_ok && (c0 <= CSR_STRIDE) && (c1 <= CSR_STRIDE);

    float acc[8];
#pragma unroll
    for (int c = 0; c < 8; ++c) acc[c] = 0.f;

    if (fits) {
        if (t < ctot) {
            const int o = (t < c0) ? 0 : 1;
            const int e = (o == 0) ? t : t - c0;
            const int j = colidx[(size_t)(o * NN + i) * CSR_STRIDE + e];
            qj[t] = j;
            qw[t] = ((o == 0) ? a0 * di0 : a1 * di1) * dinv[o * NN + j];
        }
        __syncthreads();
        for (int e = g; e < ctot; e += 16) {
            const int   j = qj[e];
            const float w = qw[e];
            const uint4 u = *(const uint4*)&xwh[(size_t)j * FF + 8 * fb];
            acc[0] += w * bflo(u.x); acc[1] += w * bfhi(u.x);
            acc[2] += w * bflo(u.y); acc[3] += w * bfhi(u.y);
            acc[4] += w * bflo(u.z); acc[5] += w * bfhi(u.z);
            acc[6] += w * bflo(u.w); acc[7] += w * bfhi(u.w);
        }
    } else {
        // Dense fallback (never expected): group g scans its column range.
        for (int o = 0; o < ORD; ++o) {
            const float  wo   = (o == 0) ? a0 * di0 : a1 * di1;
            const float* rowp = adj + (size_t)(o * NN + i) * NN;
            for (int j = g * (NN / 16); j < (g + 1) * (NN / 16); ++j) {
                const float a = rowp[j];
                if (a != 0.f && j != i) {
                    const float w = wo * dinv[o * NN + j];
                    const float* xr = &xw[(size_t)j * FF + 8 * fb];
#pragma unroll
                    for (int c = 0; c < 8; ++c) acc[c] += w * xr[c];
                }
            }
        }
    }

#pragma unroll
    for (int c = 0; c < 8; ++c) part[g][fb][c] = acc[c];
    __syncthreads();

    // Fixed binary-tree combine over the 16 groups (deterministic).
#pragma unroll
    for (int step = 8; step >= 1; step >>= 1) {
        if (g < step) {
#pragma unroll
            for (int c = 0; c < 8; ++c) part[g][fb][c] += part[g + step][fb][c];
        }
        __syncthreads();
    }

    if (t < 16) {
        const float coefd = a0 * di0 * di0 + a1 * di1 * di1;   // diagonal terms
        const float cb    = a0 + a1;                            // bias coefficient
        const float* xi = &xw[(size_t)i * FF + 8 * t];
        const float* bb = &bias[8 * t];
        float r[8];
#pragma unroll
        for (int c = 0; c < 8; ++c)
            r[c] = part[0][t][c] + coefd * xi[c] + cb * bb[c];
        *(float4*)&out[(size_t)i * FF + 8 * t]     = make_float4(r[0], r[1], r[2], r[3]);
        *(float4*)&out[(size_t)i * FF + 8 * t + 4] = make_float4(r[4], r[5], r[6], r[7]);
    }
}

// ---------------------------------------------------------------------------
extern "C" void kernel_launch(void* const* d_in, const int* in_sizes, int n_in,
                              void* d_out, int out_size, void* d_ws, size_t ws_size,
                              hipStream_t stream) {
    const float* x     = (const float*)d_in[0];
    // d_in[1] = edge_index (int64) -- unused by the math
    const float* adj   = (const float*)d_in[2];
    const float* W     = (const float*)d_in[3];
    const float* bias  = (const float*)d_in[4];
    const float* alpha = (const float*)d_in[5];
    float* out         = (float*)d_out;

    // Workspace layout
    char* ws = (char*)d_ws;
    size_t off = 0;
    float*          xw     = (float*)(ws + off); off += (size_t)NN * FF * sizeof(float);          // 4 MiB
    unsigned short* xwh    = (unsigned short*)(ws + off); off += (size_t)NN * FF * sizeof(short); // 2 MiB
    float*          dinv   = (float*)(ws + off); off += (size_t)ORD * NN * sizeof(float);         // 64 KiB
    int*            cnt    = (int*)(ws + off);   off += (size_t)ORD * NN * sizeof(int);           // 64 KiB
    int*            colidx = (int*)(ws + off);   off += (size_t)ORD * NN * CSR_STRIDE * sizeof(int); // 8 MiB
    const int csr_ok = (ws_size >= off) ? 1 : 0;

    hipLaunchKernelGGL(kernelA, dim3(SCAN_BLOCKS + XW_BLOCKS), dim3(256), 0, stream,
                       adj, x, W, xw, xwh, dinv, cnt, colidx, csr_ok);
    hipLaunchKernelGGL(kernelB, dim3(NN), dim3(256), 0, stream,
                       adj, xw, xwh, dinv, cnt, colidx, bias, alpha, out, csr_ok);
}

// Round 7
// 112.051 us; speedup vs baseline: 1.7515x; 1.0079x over previous
//
#include <hip/hip_runtime.h>
#include <math.h>

// Problem constants (from reference)
#define NN 8192
#define FF 128
#define ORD 2
#define CSR_STRIDE 128     // per-row column-index capacity; mean nnz ~33, P(>128) ~ 0
#define XW_ROWS 16         // rows per xw-role block
#define XW_BLOCKS (NN / XW_ROWS)      // 512
#define SCAN_BLOCKS 1024              // 4 waves/block
#define ROWS_PER_WAVE 4
#define NWAVES (SCAN_BLOCKS * 4)      // 4096 waves x 4 rows = 16384 rows

typedef float __attribute__((ext_vector_type(4))) f4;

// bf16 RNE encode / exact decode (bf16 = top 16 bits of f32)
__device__ __forceinline__ unsigned short f2bf(float v) {
    const unsigned int u = __float_as_uint(v);
    return (unsigned short)((u + 0x7FFFu + ((u >> 16) & 1u)) >> 16);
}
__device__ __forceinline__ float bflo(unsigned int u) { return __uint_as_float(u << 16); }
__device__ __forceinline__ float bfhi(unsigned int u) { return __uint_as_float(u & 0xFFFF0000u); }

// ---------------------------------------------------------------------------
// Kernel A: blocks [0, SCAN_BLOCKS) scan BOTH orders (wave-autonomous, no LDS,
// no barriers); blocks [SCAN_BLOCKS, +XW_BLOCKS) compute xw = x@W at the TAIL
// of the grid (fills the scan's retirement shadow).
// Scan: the (row, chunk) space is flattened into one 16-step software
// pipeline with prefetch distance 2 (16 nt-loads in flight at ALL times,
// including across row boundaries and through the prefix-scan/CSR tail).
// ---------------------------------------------------------------------------
__global__ __launch_bounds__(256) void kernelA(
    const float* __restrict__ adj, const float* __restrict__ x,
    const float* __restrict__ W,
    float* __restrict__ xw, unsigned short* __restrict__ xwh,
    float* __restrict__ dinv, int* __restrict__ cnt,
    int* __restrict__ colidx, int csr_ok)
{
    const int t = threadIdx.x;

    if (blockIdx.x >= SCAN_BLOCKS) {
        // ---------------- xw role: 16 rows x 128 cols per block -------------
        const int row0 = (blockIdx.x - SCAN_BLOCKS) * XW_ROWS;
        __shared__ float xsT[FF * 20];   // x tile transposed, [k][r], stride 20
        for (int idx = t; idx < XW_ROWS * FF; idx += 256) {
            const int r = idx >> 7, k = idx & 127;
            xsT[k * 20 + r] = x[(size_t)(row0 + r) * FF + k];
        }
        __syncthreads();
        const int f = t & 127;
        const int h = t >> 7;            // rows h*8 .. h*8+7
        float acc[8];
#pragma unroll
        for (int r = 0; r < 8; ++r) acc[r] = 0.f;
#pragma unroll 4
        for (int k = 0; k < FF; ++k) {
            const float wk = W[k * FF + f];
            const float4* xp = (const float4*)&xsT[k * 20 + h * 8];
            const float4 a0 = xp[0], a1 = xp[1];
            acc[0] += a0.x * wk; acc[1] += a0.y * wk;
            acc[2] += a0.z * wk; acc[3] += a0.w * wk;
            acc[4] += a1.x * wk; acc[5] += a1.y * wk;
            acc[6] += a1.z * wk; acc[7] += a1.w * wk;
        }
#pragma unroll
        for (int r = 0; r < 8; ++r) {
            const size_t idx = (size_t)(row0 + h * 8 + r) * FF + f;
            xw[idx]  = acc[r];
            xwh[idx] = f2bf(acc[r]);
        }
        return;
    }

    // ---------------- scan role: wave-autonomous, cross-row pipelined -------
    const int wave_id = blockIdx.x * 4 + (t >> 6);
    const int lane = t & 63;
    const int b4l  = 4 * lane;

    // Row base pointers (k-th row handled by this wave).
    const f4* rp[ROWS_PER_WAVE];
#pragma unroll
    for (int k = 0; k < ROWS_PER_WAVE; ++k)
        rp[k] = (const f4*)(adj + (size_t)(k * NWAVES + wave_id) * NN) + lane;

    f4 buf[2][8];
    unsigned int m[4];

    // Prologue: preload pipeline steps 0 and 1 (row 0, chunks 0 and 1).
#pragma unroll
    for (int s = 0; s < 8; ++s) buf[0][s] = __builtin_nontemporal_load(rp[0] + s * 64);
#pragma unroll
    for (int s = 0; s < 8; ++s) buf[1][s] = __builtin_nontemporal_load(rp[0] + 512 + s * 64);

#pragma unroll
    for (int g = 0; g < 4 * ROWS_PER_WAVE; ++g) {
        const int k  = g >> 2;
        const int ch = g & 3;

        // Consume buffer g&1 (compiler emits counted s_waitcnt vmcnt(8)).
        unsigned int mm = 0;
#pragma unroll
        for (int s = 0; s < 8; ++s) {
            const f4 vv = buf[g & 1][s];
#pragma unroll
            for (int e = 0; e < 4; ++e)
                if (vv[e] != 0.f) mm |= 1u << (4 * s + e);
        }

        // Refill the just-freed buffer with pipeline step g+2.
        if (g + 2 < 4 * ROWS_PER_WAVE) {
            const int gn = g + 2;
            const f4* src = rp[gn >> 2] + (gn & 3) * 512;
#pragma unroll
            for (int s = 0; s < 8; ++s)
                buf[g & 1][s] = __builtin_nontemporal_load(src + s * 64);
        }

        m[ch] = mm;

        if (ch == 3) {
            // ---- row finish: runs with the next row's 16 loads in flight ----
            const int r = k * NWAVES + wave_id;   // global row (o = r>>13)
            const int i = r & (NN - 1);

            // Clear the diagonal bit (column i). Static indexing into m[].
            {
                const int p_i    = i >> 2;
                const int lane_i = p_i & 63;
                const int ch_i   = p_i >> 9;
                const unsigned int bit = 1u << (4 * ((p_i >> 6) & 7) + (i & 3));
#pragma unroll
                for (int c2 = 0; c2 < 4; ++c2)
                    if (c2 == ch_i && lane == lane_i) m[c2] &= ~bit;
            }

            const int c = __popc(m[0]) + __popc(m[1]) + __popc(m[2]) + __popc(m[3]);

            // Wave-level inclusive prefix scan — no LDS, no barrier.
            int incl = c;
#pragma unroll
            for (int d = 1; d < 64; d <<= 1) {
                const int n = __shfl_up(incl, d);
                if (lane >= d) incl += n;
            }
            const int total = __shfl(incl, 63);

            if (lane == 0) {
                cnt[r]  = total;
                dinv[r] = 1.0f / sqrtf((float)(total + 1));   // deg = total + 1
            }

            if (csr_ok && total <= CSR_STRIDE) {
                int* outp = colidx + (size_t)r * CSR_STRIDE + (incl - c);
#pragma unroll
                for (int c2 = 0; c2 < 4; ++c2) {
                    unsigned int mq = m[c2];
                    while (mq) {
                        const int bq = __builtin_ctz(mq);
                        mq &= mq - 1;
                        *outp++ = c2 * 2048 + ((bq >> 2) << 8) + b4l + (bq & 3);
                    }
                }
            }
        }
    }
}

// ---------------------------------------------------------------------------
// Kernel B: gather both orders + combine. One block per output row i,
// 256 threads = 16 groups x 16 lanes; lane fb owns features 8fb..8fb+7
// (one uint4 = 8 bf16 per row read -> full 256B/wave). Both orders folded
// into one entry list with pre-scaled weights; diagonal uses exact f32 xw.
// Fixed tree combine -> deterministic FP order.
// ---------------------------------------------------------------------------
__global__ __launch_bounds__(256) void kernelB(
    const float* __restrict__ adj, const float* __restrict__ xw,
    const unsigned short* __restrict__ xwh,
    const float* __restrict__ dinv, const int* __restrict__ cnt,
    const int* __restrict__ colidx, const float* __restrict__ bias,
    const float* __restrict__ alpha, float* __restrict__ out, int csr_ok)
{
    const int i  = blockIdx.x;
    const int t  = threadIdx.x;
    const int fb = t & 15;       // feature block (8 floats)
    const int g  = t >> 4;       // entry group 0..15

    __shared__ int   qj[2 * CSR_STRIDE];
    __shared__ float qw[2 * CSR_STRIDE];
    __shared__ float part[16][16][8];

    const int   c0  = cnt[i],  c1  = cnt[NN + i];
    const float di0 = dinv[i], di1 = dinv[NN + i];
    const float a0  = alpha[0], a1 = alpha[1];
    const int   ctot = c0 + c1;
    const int   fits = csr_ok && (c0 <= CSR_STRIDE) && (c1 <= CSR_STRIDE);

    float acc[8];
#pragma unroll
    for (int c = 0; c < 8; ++c) acc[c] = 0.f;

    if (fits) {
        if (t < ctot) {
            const int o = (t < c0) ? 0 : 1;
            const int e = (o == 0) ? t : t - c0;
            const int j = colidx[(size_t)(o * NN + i) * CSR_STRIDE + e];
            qj[t] = j;
            qw[t] = ((o == 0) ? a0 * di0 : a1 * di1) * dinv[o * NN + j];
        }
        __syncthreads();
        for (int e = g; e < ctot; e += 16) {
            const int   j = qj[e];
            const float w = qw[e];
            const uint4 u = *(const uint4*)&xwh[(size_t)j * FF + 8 * fb];
            acc[0] += w * bflo(u.x); acc[1] += w * bfhi(u.x);
            acc[2] += w * bflo(u.y); acc[3] += w * bfhi(u.y);
            acc[4] += w * bflo(u.z); acc[5] += w * bfhi(u.z);
            acc[6] += w * bflo(u.w); acc[7] += w * bfhi(u.w);
        }
    } else {
        // Dense fallback (never expected): group g scans its column range.
        for (int o = 0; o < ORD; ++o) {
            const float  wo   = (o == 0) ? a0 * di0 : a1 * di1;
            const float* rowp = adj + (size_t)(o * NN + i) * NN;
            for (int j = g * (NN / 16); j < (g + 1) * (NN / 16); ++j) {
                const float a = rowp[j];
                if (a != 0.f && j != i) {
                    const float w = wo * dinv[o * NN + j];
                    const float* xr = &xw[(size_t)j * FF + 8 * fb];
#pragma unroll
                    for (int c = 0; c < 8; ++c) acc[c] += w * xr[c];
                }
            }
        }
    }

#pragma unroll
    for (int c = 0; c < 8; ++c) part[g][fb][c] = acc[c];
    __syncthreads();

    // Fixed binary-tree combine over the 16 groups (deterministic).
#pragma unroll
    for (int step = 8; step >= 1; step >>= 1) {
        if (g < step) {
#pragma unroll
            for (int c = 0; c < 8; ++c) part[g][fb][c] += part[g + step][fb][c];
        }
        __syncthreads();
    }

    if (t < 16) {
        const float coefd = a0 * di0 * di0 + a1 * di1 * di1;   // diagonal terms
        const float cb    = a0 + a1;                            // bias coefficient
        const float* xi = &xw[(size_t)i * FF + 8 * t];
        const float* bb = &bias[8 * t];
        float r[8];
#pragma unroll
        for (int c = 0; c < 8; ++c)
            r[c] = part[0][t][c] + coefd * xi[c] + cb * bb[c];
        *(float4*)&out[(size_t)i * FF + 8 * t]     = make_float4(r[0], r[1], r[2], r[3]);
        *(float4*)&out[(size_t)i * FF + 8 * t + 4] = make_float4(r[4], r[5], r[6], r[7]);
    }
}

// ---------------------------------------------------------------------------
extern "C" void kernel_launch(void* const* d_in, const int* in_sizes, int n_in,
                              void* d_out, int out_size, void* d_ws, size_t ws_size,
                              hipStream_t stream) {
    const float* x     = (const float*)d_in[0];
    // d_in[1] = edge_index (int64) -- unused by the math
    const float* adj   = (const float*)d_in[2];
    const float* W     = (const float*)d_in[3];
    const float* bias  = (const float*)d_in[4];
    const float* alpha = (const float*)d_in[5];
    float* out         = (float*)d_out;

    // Workspace layout
    char* ws = (char*)d_ws;
    size_t off = 0;
    float*          xw     = (float*)(ws + off); off += (size_t)NN * FF * sizeof(float);          // 4 MiB
    unsigned short* xwh    = (unsigned short*)(ws + off); off += (size_t)NN * FF * sizeof(short); // 2 MiB
    float*          dinv   = (float*)(ws + off); off += (size_t)ORD * NN * sizeof(float);         // 64 KiB
    int*            cnt    = (int*)(ws + off);   off += (size_t)ORD * NN * sizeof(int);           // 64 KiB
    int*            colidx = (int*)(ws + off);   off += (size_t)ORD * NN * CSR_STRIDE * sizeof(int); // 8 MiB
    const int csr_ok = (ws_size >= off) ? 1 : 0;

    hipLaunchKernelGGL(kernelA, dim3(SCAN_BLOCKS + XW_BLOCKS), dim3(256), 0, stream,
                       adj, x, W, xw, xwh, dinv, cnt, colidx, csr_ok);
    hipLaunchKernelGGL(kernelB, dim3(NN), dim3(256), 0, stream,
                       adj, xw, xwh, dinv, cnt, colidx, bias, alpha, out, csr_ok);
}